// Round 1
// baseline (548.856 us; speedup 1.0000x reference)
//
#include <hip/hip_runtime.h>
#include <math.h>

// Problem constants (CBOW_5205500363137)
#define BB     65536
#define KK     10
#define EE     128
#define NBLK   512    // 2 blocks/CU: fewer concurrent DRAM streams (tuned earlier)
#define ITERS  8      // 512 blocks * 8 iters * 16 rows = 65536

typedef float f4 __attribute__((ext_vector_type(4)));

// Non-temporal (evict-first) load for the use-once mask streams.
__device__ __forceinline__ f4 ldnt(const float* p) {
    return __builtin_nontemporal_load((const f4*)p);
}
// Normal cached load (embedding tables: reused via L2/L3).
__device__ __forceinline__ f4 ldg4(const float* p) {
    return *(const f4*)p;
}

__device__ __forceinline__ float log_sigmoid_f(float x) {
    // log(sigmoid(x)) = min(x, 0) - log1p(exp(-|x|))   (numerically stable)
    return fminf(x, 0.0f) - log1pf(expf(-fabsf(x)));
}

__device__ __forceinline__ float dot4(f4 a, f4 b, float acc) {
    acc = fmaf(a.x, b.x, acc);
    acc = fmaf(a.y, b.y, acc);
    acc = fmaf(a.z, b.z, acc);
    acc = fmaf(a.w, b.w, acc);
    return acc;
}

// 2 rows per half-wave per iteration: doubles memory-level parallelism per
// wave (we are grid-limited to 2 waves/SIMD, so VGPR budget up to 256 is
// free). Index loads for iteration gi+1 are rotated in registers so the
// dependent gathers of each iteration issue without an index-load stall.
__global__ __launch_bounds__(256, 2) void cbow_main(
    const int*   __restrict__ ctx_words,   // [B]
    const int*   __restrict__ tgt_words,   // [B]
    const int*   __restrict__ neg_words,   // [B,K]
    const float* __restrict__ V_emb,       // [VOCAB,E]
    const float* __restrict__ U_emb,       // [VOCAB,E]
    const float* __restrict__ mask_v,      // [B,E]
    const float* __restrict__ mask_u,      // [B,E]
    const float* __restrict__ mask_neg,    // [B,K,E]
    double*      __restrict__ partials)    // [NBLK]
{
    const int t    = threadIdx.x;
    const int sub  = t >> 5;    // 0..7: half-wave id within block
    const int lane = t & 31;    // lane within the 32-lane half-wave
    const int kidx = lane & 15; // 0..15: neg-index slot within row half
    const int ksel = (kidx < KK) ? kidx : 0;

    double local = 0.0;

    // --- indices for gi = 0 ---
    int row0 = (blockIdx.x * ITERS + 0) * 16 + sub * 2;
    int row1 = row0 + 1;
    int c0  = ctx_words[row0];
    int c1  = ctx_words[row1];
    int tg0 = tgt_words[row0];
    int tg1 = tgt_words[row1];
    // lanes 0..9 hold row0's 10 neg indices; lanes 16..25 hold row1's
    int nid = neg_words[(size_t)(lane >= 16 ? row1 : row0) * KK + ksel];

    for (int gi = 0; gi < ITERS; ++gi) {
        // --- prefetch indices for gi+1 (clamped on last iter; harmless) ---
        const int gin   = (gi + 1 < ITERS) ? (gi + 1) : gi;
        const int nrow0 = (blockIdx.x * ITERS + gin) * 16 + sub * 2;
        const int nrow1 = nrow0 + 1;
        const int c0n   = ctx_words[nrow0];
        const int c1n   = ctx_words[nrow1];
        const int tg0n  = tgt_words[nrow0];
        const int tg1n  = tgt_words[nrow1];
        const int nidn  = neg_words[(size_t)(lane >= 16 ? nrow1 : nrow0) * KK + ksel];

        // --- v = V_emb[ctx] * mask_v[row] for both rows ---
        const f4 ve0 = ldg4(V_emb  + (size_t)c0   * EE + lane * 4);
        const f4 mv0 = ldnt(mask_v + (size_t)row0 * EE + lane * 4);
        const f4 ve1 = ldg4(V_emb  + (size_t)c1   * EE + lane * 4);
        const f4 mv1 = ldnt(mask_v + (size_t)row1 * EE + lane * 4);
        const f4 v0  = ve0 * mv0;
        const f4 v1  = ve1 * mv1;

        // --- pos partials ---
        const f4 ue0 = ldg4(U_emb  + (size_t)tg0  * EE + lane * 4);
        const f4 mu0 = ldnt(mask_u + (size_t)row0 * EE + lane * 4);
        const f4 ue1 = ldg4(U_emb  + (size_t)tg1  * EE + lane * 4);
        const f4 mu1 = ldnt(mask_u + (size_t)row1 * EE + lane * 4);
        float pos0 = dot4(ue0 * mu0, v0, 0.0f);
        float pos1 = dot4(ue1 * mu1, v1, 0.0f);

        // --- neg partials: 20 independent gather+mask pairs in flight ---
        float neg0 = 0.0f, neg1 = 0.0f;
#pragma unroll
        for (int k = 0; k < KK; ++k) {
            const int nk0 = __shfl(nid, k,      32);
            const int nk1 = __shfl(nid, 16 + k, 32);
            const f4 ne0 = ldg4(U_emb    + (size_t)nk0 * EE + lane * 4);
            const f4 mn0 = ldnt(mask_neg + ((size_t)row0 * KK + k) * EE + lane * 4);
            const f4 ne1 = ldg4(U_emb    + (size_t)nk1 * EE + lane * 4);
            const f4 mn1 = ldnt(mask_neg + ((size_t)row1 * KK + k) * EE + lane * 4);
            neg0 = dot4(ne0 * mn0, v0, neg0);
            neg1 = dot4(ne1 * mn1, v1, neg1);
        }

        // --- reduce within the 32-lane half (xor masks <=16 stay inside) ---
#pragma unroll
        for (int m = 16; m >= 1; m >>= 1) {
            pos0 += __shfl_xor(pos0, m, 64);
            neg0 += __shfl_xor(neg0, m, 64);
            pos1 += __shfl_xor(pos1, m, 64);
            neg1 += __shfl_xor(neg1, m, 64);
        }

        if (lane == 0) {
            local += (double)(log_sigmoid_f(pos0) + log_sigmoid_f(-neg0)
                            + log_sigmoid_f(pos1) + log_sigmoid_f(-neg1));
        }

        // rotate prefetched indices into place
        row0 = nrow0; row1 = nrow1;
        c0 = c0n; c1 = c1n; tg0 = tg0n; tg1 = tg1n; nid = nidn;
    }

    // Block reduction: 8 half-wave leaders -> one double per block
    __shared__ double sbuf[8];
    if (lane == 0) sbuf[sub] = local;
    __syncthreads();
    if (t == 0) {
        double s = 0.0;
#pragma unroll
        for (int i = 0; i < 8; ++i) s += sbuf[i];
        partials[blockIdx.x] = s;
    }
}

__global__ __launch_bounds__(256) void cbow_reduce(
    const double* __restrict__ partials, float* __restrict__ out)
{
    __shared__ double sbuf[256];
    double s = 0.0;
    for (int i = threadIdx.x; i < NBLK; i += 256) s += partials[i];
    sbuf[threadIdx.x] = s;
    __syncthreads();
    for (int stride = 128; stride > 0; stride >>= 1) {
        if (threadIdx.x < stride) sbuf[threadIdx.x] += sbuf[threadIdx.x + stride];
        __syncthreads();
    }
    if (threadIdx.x == 0) out[0] = (float)(-sbuf[0] / (double)BB);
}

extern "C" void kernel_launch(void* const* d_in, const int* in_sizes, int n_in,
                              void* d_out, int out_size, void* d_ws, size_t ws_size,
                              hipStream_t stream) {
    const int*   ctx_words = (const int*)  d_in[0];
    const int*   tgt_words = (const int*)  d_in[1];
    const int*   neg_words = (const int*)  d_in[2];
    const float* V_emb     = (const float*)d_in[3];
    const float* U_emb     = (const float*)d_in[4];
    const float* mask_v    = (const float*)d_in[5];
    const float* mask_u    = (const float*)d_in[6];
    const float* mask_neg  = (const float*)d_in[7];
    float*       out       = (float*)d_out;
    double*      partials  = (double*)d_ws;   // needs NBLK*8 = 4 KiB of ws

    cbow_main<<<NBLK, 256, 0, stream>>>(ctx_words, tgt_words, neg_words,
                                        V_emb, U_emb, mask_v, mask_u, mask_neg,
                                        partials);
    cbow_reduce<<<1, 256, 0, stream>>>(partials, out);
}

// Round 2
// 547.310 us; speedup vs baseline: 1.0028x; 1.0028x over previous
//
#include <hip/hip_runtime.h>
#include <math.h>

// Problem constants (CBOW_5205500363137)
#define BB     65536
#define KK     10
#define EE     128
#define NBLK   2048   // 4 blocks/CU, 16 waves/CU: test BW-concurrency theory
#define ITERS  4      // 2048 blocks * 4 iters * 8 rows = 65536

typedef float f4 __attribute__((ext_vector_type(4)));

// Non-temporal (evict-first) load for the use-once mask streams.
__device__ __forceinline__ f4 ldnt(const float* p) {
    return __builtin_nontemporal_load((const f4*)p);
}
// Normal cached load (embedding tables: reused via L2/L3).
__device__ __forceinline__ f4 ldg4(const float* p) {
    return *(const f4*)p;
}

__device__ __forceinline__ float log_sigmoid_f(float x) {
    // log(sigmoid(x)) = min(x, 0) - log1p(exp(-|x|))   (numerically stable)
    return fminf(x, 0.0f) - log1pf(expf(-fabsf(x)));
}

// __launch_bounds__(256, 4): cap VGPRs at 128 so 4 waves/SIMD are resident.
__global__ __launch_bounds__(256, 4) void cbow_main(
    const int*   __restrict__ ctx_words,   // [B]
    const int*   __restrict__ tgt_words,   // [B]
    const int*   __restrict__ neg_words,   // [B,K]
    const float* __restrict__ V_emb,       // [VOCAB,E]
    const float* __restrict__ U_emb,       // [VOCAB,E]
    const float* __restrict__ mask_v,      // [B,E]
    const float* __restrict__ mask_u,      // [B,E]
    const float* __restrict__ mask_neg,    // [B,K,E]
    double*      __restrict__ partials)    // [NBLK]
{
    const int t    = threadIdx.x;
    const int sub  = t >> 5;    // 0..7: half-wave id within block (one row each)
    const int lane = t & 31;    // lane within the 32-lane half-wave

    double local = 0.0;

    for (int gi = 0; gi < ITERS; ++gi) {
        const int row = (blockIdx.x * ITERS + gi) * 8 + sub;

        const int ctx = ctx_words[row];
        const int tgt = tgt_words[row];
        // lanes 0..9 hold the 10 negative indices; broadcast via shfl below
        const int nidx = neg_words[(size_t)row * KK + (lane < KK ? lane : 0)];

        // v = V_emb[ctx] * mask_v[row]   (each lane holds 4 consecutive floats)
        const f4 ve = ldg4(V_emb  + (size_t)ctx * EE + lane * 4);
        const f4 mv = ldnt(mask_v + (size_t)row * EE + lane * 4);
        const f4 v  = ve * mv;

        // u = U_emb[tgt] * mask_u[row]; pos partial = dot(u, v)
        const f4 ue = ldg4(U_emb  + (size_t)tgt * EE + lane * 4);
        const f4 mu = ldnt(mask_u + (size_t)row * EE + lane * 4);
        const f4 up = ue * mu;
        float posp = fmaf(up.x, v.x, fmaf(up.y, v.y, fmaf(up.z, v.z, up.w * v.w)));

        // negp = sum_k dot(U_emb[nk]*mask_neg[row,k], v)
        float negp = 0.0f;
#pragma unroll
        for (int k = 0; k < KK; ++k) {
            const int nk = __shfl(nidx, k, 32);
            const f4 ne = ldg4(U_emb + (size_t)nk * EE + lane * 4);
            const f4 mn = ldnt(mask_neg + ((size_t)row * KK + k) * EE + lane * 4);
            const f4 np = ne * mn;
            negp = fmaf(np.x, v.x, negp);
            negp = fmaf(np.y, v.y, negp);
            negp = fmaf(np.z, v.z, negp);
            negp = fmaf(np.w, v.w, negp);
        }

        // Reduce within the 32-lane half (xor masks <=16 stay inside each half)
        float pos = posp, neg = negp;
#pragma unroll
        for (int m = 16; m >= 1; m >>= 1) {
            pos += __shfl_xor(pos, m, 64);
            neg += __shfl_xor(neg, m, 64);
        }

        if (lane == 0) {
            local += (double)(log_sigmoid_f(pos) + log_sigmoid_f(-neg));
        }
    }

    // Block reduction: 8 half-wave leaders -> one double per block
    __shared__ double sbuf[8];
    if (lane == 0) sbuf[sub] = local;
    __syncthreads();
    if (t == 0) {
        double s = 0.0;
#pragma unroll
        for (int i = 0; i < 8; ++i) s += sbuf[i];
        partials[blockIdx.x] = s;
    }
}

__global__ __launch_bounds__(256) void cbow_reduce(
    const double* __restrict__ partials, float* __restrict__ out)
{
    __shared__ double sbuf[256];
    double s = 0.0;
    for (int i = threadIdx.x; i < NBLK; i += 256) s += partials[i];
    sbuf[threadIdx.x] = s;
    __syncthreads();
    for (int stride = 128; stride > 0; stride >>= 1) {
        if (threadIdx.x < stride) sbuf[threadIdx.x] += sbuf[threadIdx.x + stride];
        __syncthreads();
    }
    if (threadIdx.x == 0) out[0] = (float)(-sbuf[0] / (double)BB);
}

extern "C" void kernel_launch(void* const* d_in, const int* in_sizes, int n_in,
                              void* d_out, int out_size, void* d_ws, size_t ws_size,
                              hipStream_t stream) {
    const int*   ctx_words = (const int*)  d_in[0];
    const int*   tgt_words = (const int*)  d_in[1];
    const int*   neg_words = (const int*)  d_in[2];
    const float* V_emb     = (const float*)d_in[3];
    const float* U_emb     = (const float*)d_in[4];
    const float* mask_v    = (const float*)d_in[5];
    const float* mask_u    = (const float*)d_in[6];
    const float* mask_neg  = (const float*)d_in[7];
    float*       out       = (float*)d_out;
    double*      partials  = (double*)d_ws;   // needs NBLK*8 = 16 KiB of ws

    cbow_main<<<NBLK, 256, 0, stream>>>(ctx_words, tgt_words, neg_words,
                                        V_emb, U_emb, mask_v, mask_u, mask_neg,
                                        partials);
    cbow_reduce<<<1, 256, 0, stream>>>(partials, out);
}